// Round 20
// baseline (389.302 us; speedup 1.0000x reference)
//
#include <hip/hip_runtime.h>
#include <math.h>

#define SS 2048

typedef __attribute__((ext_vector_type(8))) short s16x8;
typedef __attribute__((ext_vector_type(4))) float f32x4;
typedef __attribute__((ext_vector_type(16))) float f32x16;

__device__ __forceinline__ unsigned short f2bf(float f) {
  union { float f; unsigned u; } a; a.f = f;
  unsigned r = a.u + 0x7fffu + ((a.u >> 16) & 1u);   // RNE
  return (unsigned short)(r >> 16);
}
__device__ __forceinline__ float bf2f(unsigned short b) {
  union { unsigned u; float f; } a; a.u = ((unsigned)b) << 16;
  return a.f;
}
// packed f32->bf16 (RNE): dword = {lo: bf16(a), hi: bf16(b)}
__device__ __forceinline__ unsigned cvtpk(float a, float b) {
  unsigned d; asm("v_cvt_pk_bf16_f32 %0, %1, %2" : "=v"(d) : "v"(a), "v"(b)); return d;
}
// raw v_exp_f32 = 2^x
__device__ __forceinline__ float fexp2(float x) {
  float r; asm("v_exp_f32 %0, %1" : "=v"(r) : "v"(x)); return r;
}
__device__ __forceinline__ void async16(void* lds, const void* g) {
  __builtin_amdgcn_global_load_lds(
      (const __attribute__((address_space(1))) unsigned int*)g,
      (__attribute__((address_space(3))) unsigned int*)lds, 16, 0, 0);
}
__device__ __forceinline__ f32x4 mfma_bf16(s16x8 a, s16x8 b, f32x4 c) {
  return __builtin_amdgcn_mfma_f32_16x16x32_bf16(a, b, c, 0, 0, 0);
}
__device__ __forceinline__ f32x16 mfma32(s16x8 a, s16x8 b, f32x16 c) {
  return __builtin_amdgcn_mfma_f32_32x32x16_bf16(a, b, c, 0, 0, 0);
}
// XCD-aware bijective blockIdx swizzle (T1); requires nwg % 8 == 0
__device__ __forceinline__ void xcd_swz(int& bx, int& by) {
  int nx = gridDim.x;
  int nwg = nx * gridDim.y;
  int bid = blockIdx.y * nx + blockIdx.x;
  int sid = (bid & 7) * (nwg >> 3) + (bid >> 3);
  bx = sid % nx; by = sid / nx;
}

// ---------- transpose + fp32->bf16: WT[n][k] = bf16(W[k][n]); z selects pair ----------
__global__ __launch_bounds__(256) void k_transpose(const float* __restrict__ W,
                                                   const float* __restrict__ W2,
                                                   unsigned short* __restrict__ WT,
                                                   unsigned short* __restrict__ WT2,
                                                   int K, int N) {
  const float* Wp = blockIdx.z ? W2 : W;
  unsigned short* WTp = blockIdx.z ? WT2 : WT;
  __shared__ float tile[32][33];
  int t = threadIdx.x;
  int tx = t & 31, ty = t >> 5;
  int n0 = blockIdx.x * 32, k0 = blockIdx.y * 32;
#pragma unroll
  for (int i = 0; i < 4; ++i)
    tile[ty + 8 * i][tx] = Wp[(size_t)(k0 + ty + 8 * i) * N + n0 + tx];
  __syncthreads();
#pragma unroll
  for (int i = 0; i < 4; ++i)
    WTp[(size_t)(n0 + ty + 8 * i) * K + k0 + tx] = f2bf(tile[tx][ty + 8 * i]);
}

// ---------- V^T precompute: VT[(b*4+kvh)][d=64][s=2048] from QKV cols 1280.. ----------
__global__ __launch_bounds__(256) void k_vtrans(const unsigned short* __restrict__ QKV,
                                                unsigned short* __restrict__ VT) {
  __shared__ unsigned short tile[32][33];
  int t = threadIdx.x, tx = t & 31, ty = t >> 5;
  int s0 = blockIdx.x * 32, d0 = blockIdx.y * 32;
  int bk = blockIdx.z; int b = bk >> 2, kvh = bk & 3;
#pragma unroll
  for (int i = 0; i < 4; ++i)
    tile[ty + 8 * i][tx] =
        QKV[((size_t)b * SS + s0 + ty + 8 * i) * 1536 + 1280 + kvh * 64 + d0 + tx];
  __syncthreads();
#pragma unroll
  for (int i = 0; i < 4; ++i)
    VT[((size_t)bk * 64 + d0 + ty + 8 * i) * SS + s0 + tx] = tile[tx][ty + 8 * i];
}

// ---------- RoPE tables (double precision, once per launch) ----------
__global__ void k_rope_tables(float* __restrict__ cosT, float* __restrict__ sinT) {
  int idx = blockIdx.x * 256 + threadIdx.x;  // 65536 = 2048*32
  int s = idx >> 5, i = idx & 31;
  double ang = (double)s * pow(10000.0, -(double)(2 * i) / 64.0);
  cosT[idx] = (float)cos(ang);
  sinT[idx] = (float)sin(ang);
}

// ---------- RMSNorm fp32 -> bf16; rows >= 4096 come from the second stream ----------
__global__ __launch_bounds__(256) void k_rmsnorm(const float* __restrict__ X,
                                                 const float* __restrict__ X2,
                                                 const float* __restrict__ Wt,
                                                 unsigned short* __restrict__ Y,
                                                 unsigned short* __restrict__ Y2) {
  int row = blockIdx.x, t = threadIdx.x;
  const float* Xp = X;
  unsigned short* Yp = Y;
  if (X2 && row >= 4096) { Xp = X2; Yp = Y2; row -= 4096; }
  float4 v = ((const float4*)Xp)[(size_t)row * 256 + t];
  float ssq = v.x * v.x + v.y * v.y + v.z * v.z + v.w * v.w;
#pragma unroll
  for (int m = 1; m < 64; m <<= 1) ssq += __shfl_xor(ssq, m);
  __shared__ float red[4];
  if ((t & 63) == 0) red[t >> 6] = ssq;
  __syncthreads();
  float sc = rsqrtf((red[0] + red[1] + red[2] + red[3]) * (1.0f / 1024.0f) + 1e-6f);
  float4 wv = ((const float4*)Wt)[t];
  ushort4 o;
  o.x = f2bf(v.x * sc * wv.x); o.y = f2bf(v.y * sc * wv.y);
  o.z = f2bf(v.z * sc * wv.z); o.w = f2bf(v.w * sc * wv.w);
  ((ushort4*)Yp)[(size_t)row * 256 + t] = o;
}

// ---------- RoPE in place on QKV buffer; head = blockIdx.y + hbase ----------
__global__ __launch_bounds__(256) void k_rope(unsigned short* __restrict__ X,
                                              const float* __restrict__ cosT,
                                              const float* __restrict__ sinT,
                                              int stride, int hbase) {
  int idx = blockIdx.x * 256 + threadIdx.x;  // tok*8+seg, tok 0..4095
  int seg = idx & 7, tok = idx >> 3;
  int head = blockIdx.y + hbase;
  int s = tok & (SS - 1);
  int d0 = seg * 4;
  unsigned short* p = X + (size_t)tok * stride + head * 64;
  ushort4 lo = *(ushort4*)&p[d0];
  ushort4 hi = *(ushort4*)&p[d0 + 32];
  float4 cs = *(const float4*)&cosT[s * 32 + d0];
  float4 sn = *(const float4*)&sinT[s * 32 + d0];
  ushort4 olo, ohi;
  olo.x = f2bf(bf2f(lo.x) * cs.x - bf2f(hi.x) * sn.x);
  olo.y = f2bf(bf2f(lo.y) * cs.y - bf2f(hi.y) * sn.y);
  olo.z = f2bf(bf2f(lo.z) * cs.z - bf2f(hi.z) * sn.z);
  olo.w = f2bf(bf2f(lo.w) * cs.w - bf2f(hi.w) * sn.w);
  ohi.x = f2bf(bf2f(hi.x) * cs.x + bf2f(lo.x) * sn.x);
  ohi.y = f2bf(bf2f(hi.y) * cs.y + bf2f(lo.y) * sn.y);
  ohi.z = f2bf(bf2f(hi.z) * cs.z + bf2f(lo.z) * sn.z);
  ohi.w = f2bf(bf2f(hi.w) * cs.w + bf2f(lo.w) * sn.w);
  *(ushort4*)&p[d0] = olo;
  *(ushort4*)&p[d0 + 32] = ohi;
}

// ---------- GEMM: C[M,N] = A[M,K](bf16) x BT[N,K](bf16), BK=64 + T2 swizzle ----------
template <int EPI, int BN>
__global__ __launch_bounds__(256) void k_gemm(const unsigned short* __restrict__ A,
                                              const unsigned short* __restrict__ BT,
                                              int K, int ldc,
                                              unsigned short* Cb,
                                              float* __restrict__ Cf,
                                              const float* __restrict__ Res) {
  constexpr int NW = BN / 32;
  __shared__ __align__(16) unsigned short at[128 * 64];
  __shared__ __align__(16) unsigned short bt[BN * 64];
  int bx, by; xcd_swz(bx, by);
  int t = threadIdx.x, w = t >> 6, l = t & 63;
  int g = l >> 4, c = l & 15;
  int wm = w >> 1, wn = w & 1;
  f32x4 acc[4][NW] = {};
  int srow = t >> 3;
  int scol = ((t & 7) ^ (srow & 7)) * 8;
  const unsigned short* gA = A + (size_t)(by * 128 + srow) * K + scol;
  const unsigned short* gB = BT + (size_t)(bx * BN + srow) * K + scol;
  unsigned short* dA = &at[w * 512];
  unsigned short* dB = &bt[w * 512];
  const int nk = K >> 6;
  for (int kt = 0; kt < nk; ++kt) {
#pragma unroll
    for (int j = 0; j < 4; ++j)
      async16(dA + j * 2048, gA + (size_t)(32 * j) * K);
#pragma unroll
    for (int j = 0; j < BN / 32; ++j)
      async16(dB + j * 2048, gB + (size_t)(32 * j) * K);
    gA += 64; gB += 64;
    __syncthreads();
    s16x8 af[4], bfr[NW];
#pragma unroll
    for (int kk = 0; kk < 2; ++kk) {
#pragma unroll
      for (int m = 0; m < 4; ++m)
        af[m] = *(const s16x8*)&at[(wm * 64 + m * 16 + c) * 64 + (((kk * 4 + g) ^ (c & 7)) << 3)];
#pragma unroll
      for (int n = 0; n < NW; ++n)
        bfr[n] = *(const s16x8*)&bt[(wn * (BN / 2) + n * 16 + c) * 64 + (((kk * 4 + g) ^ (c & 7)) << 3)];
#pragma unroll
      for (int m = 0; m < 4; ++m)
#pragma unroll
        for (int n = 0; n < NW; ++n)
          acc[m][n] = mfma_bf16(af[m], bfr[n], acc[m][n]);
    }
    __syncthreads();
  }
  size_t rb = (size_t)by * 128 + wm * 64;
  size_t cbase = (size_t)bx * BN + wn * (BN / 2);
#pragma unroll
  for (int m = 0; m < 4; ++m)
#pragma unroll
    for (int n = 0; n < NW; ++n)
#pragma unroll
      for (int r = 0; r < 4; ++r) {
        size_t row = rb + m * 16 + g * 4 + r;
        size_t col = cbase + n * 16 + c;
        float v = acc[m][n][r];
        if (EPI == 0) Cb[row * ldc + col] = f2bf(v);
        else Cf[row * ldc + col] = v + Res[row * ldc + col];
      }
}

// ---------- fused gate+up GEMM: inter = silu(A@Wg) * (A@Wu), BK=64 + T2 swizzle ----------
__global__ __launch_bounds__(512) void k_gateup(const unsigned short* __restrict__ A,
                                                const unsigned short* __restrict__ BTg,
                                                const unsigned short* __restrict__ BTu,
                                                unsigned short* __restrict__ Cb) {
  __shared__ __align__(16) unsigned short at[128 * 64];
  __shared__ __align__(16) unsigned short bg[128 * 64];
  __shared__ __align__(16) unsigned short bu[128 * 64];
  int bx, by; xcd_swz(bx, by);
  int t = threadIdx.x, w = t >> 6, l = t & 63;
  int g = l >> 4, c = l & 15;
  int wm = w >> 2, wn = w & 3;
  f32x4 ag[4][2] = {}, au[4][2] = {};
  int srow = t >> 3;
  int scol = ((t & 7) ^ (srow & 7)) * 8;
  const unsigned short* gA = A + (size_t)(by * 128 + srow) * 1024 + scol;
  const unsigned short* gG = BTg + (size_t)(bx * 128 + srow) * 1024 + scol;
  const unsigned short* gU = BTu + (size_t)(bx * 128 + srow) * 1024 + scol;
  unsigned short* dA = &at[w * 512];
  unsigned short* dG = &bg[w * 512];
  unsigned short* dU = &bu[w * 512];
  for (int kt = 0; kt < 16; ++kt) {
#pragma unroll
    for (int j = 0; j < 2; ++j) {
      async16(dA + j * 4096, gA + (size_t)(64 * j) * 1024);
      async16(dG + j * 4096, gG + (size_t)(64 * j) * 1024);
      async16(dU + j * 4096, gU + (size_t)(64 * j) * 1024);
    }
    gA += 64; gG += 64; gU += 64;
    __syncthreads();
    s16x8 af[4], bgf[2], buf_[2];
#pragma unroll
    for (int kk = 0; kk < 2; ++kk) {
#pragma unroll
      for (int m = 0; m < 4; ++m)
        af[m] = *(const s16x8*)&at[(wm * 64 + m * 16 + c) * 64 + (((kk * 4 + g) ^ (c & 7)) << 3)];
#pragma unroll
      for (int n = 0; n < 2; ++n) {
        int roff = (wn * 32 + n * 16 + c) * 64 + (((kk * 4 + g) ^ (c & 7)) << 3);
        bgf[n] = *(const s16x8*)&bg[roff];
        buf_[n] = *(const s16x8*)&bu[roff];
      }
#pragma unroll
      for (int m = 0; m < 4; ++m)
#pragma unroll
        for (int n = 0; n < 2; ++n) {
          ag[m][n] = mfma_bf16(af[m], bgf[n], ag[m][n]);
          au[m][n] = mfma_bf16(af[m], buf_[n], au[m][n]);
        }
    }
    __syncthreads();
  }
  size_t rb = (size_t)by * 128 + wm * 64;
  size_t cb = (size_t)bx * 128 + wn * 32;
#pragma unroll
  for (int m = 0; m < 4; ++m)
#pragma unroll
    for (int n = 0; n < 2; ++n)
#pragma unroll
      for (int r = 0; r < 4; ++r) {
        size_t row = rb + m * 16 + g * 4 + r;
        size_t col = cb + n * 16 + c;
        float gv = ag[m][n][r], uv = au[m][n][r];
        Cb[row * 4096 + col] = f2bf(gv / (1.0f + __expf(-gv)) * uv);
      }
}

// ---------- Flash attention: KVBLK=128 (2x64 subtiles), 1 barrier per pair ----------
// Block = 256 thr = 4 waves (4 Q-heads of one GQA group); 32 q-rows.
// LDS = 64KB dbuf of [2 subtiles][64][64] for K and VT (subtile layout keeps the
// proven XOR swizzle byte-identical: (s*64+row)&7 == row&7). Barriers 32 -> 16;
// register prefetch gets two sub-steps of latency cover.
__global__ __launch_bounds__(256) void k_attn(const unsigned short* __restrict__ Q,
                                              const unsigned short* __restrict__ K,
                                              const unsigned short* __restrict__ VT,
                                              const float* __restrict__ mask,
                                              const float* __restrict__ cosT,
                                              const float* __restrict__ sinT,
                                              unsigned short* __restrict__ Out) {
  __shared__ __align__(16) unsigned short Ks[2][8192];
  __shared__ __align__(16) unsigned short VTs[2][8192];
  const float LOG2E = 1.44269504f;
  const float SCL2 = 0.125f * 1.44269504f;
  int t = threadIdx.x, w = t >> 6, l = t & 63;
  int q32 = l & 31, hi = l >> 5;
  int blk = blockIdx.x;
  int qt = blk & 63, kvh = (blk >> 6) & 3, b = blk >> 8;
  int head = kvh * 4 + w;
  size_t tokQ = (size_t)b * SS + qt * 32;

  s16x8 qfr[4];   // Q[tokQ+q32][head*64 + d*16 + hi*8 + 0..7]
#pragma unroll
  for (int d = 0; d < 4; ++d)
    qfr[d] = *(const s16x8*)&Q[(tokQ + q32) * 1536 + head * 64 + d * 16 + hi * 8];
  // in-register RoPE on Q
  {
    int sp = qt * 32 + q32;
    const float* ct = cosT + sp * 32;
    const float* st = sinT + sp * 32;
#pragma unroll
    for (int d = 0; d < 2; ++d) {
      unsigned wlo[4], whi[4];
#pragma unroll
      for (int j = 0; j < 8; j += 2) {
        int f0 = d * 16 + hi * 8 + j;
        float c0 = ct[f0], s0_ = st[f0];
        float c1 = ct[f0 + 1], s1_ = st[f0 + 1];
        float lo0 = bf2f((unsigned short)qfr[d][j]);
        float hi0 = bf2f((unsigned short)qfr[d + 2][j]);
        float lo1 = bf2f((unsigned short)qfr[d][j + 1]);
        float hi1 = bf2f((unsigned short)qfr[d + 2][j + 1]);
        wlo[j >> 1] = cvtpk(lo0 * c0 - hi0 * s0_, lo1 * c1 - hi1 * s1_);
        whi[j >> 1] = cvtpk(hi0 * c0 + lo0 * s0_, hi1 * c1 + lo1 * s1_);
      }
      union { unsigned u[4]; s16x8 v; } a, b2;
#pragma unroll
      for (int i = 0; i < 4; ++i) { a.u[i] = wlo[i]; b2.u[i] = whi[i]; }
      qfr[d] = a.v;
      qfr[d + 2] = b2.v;
    }
  }
  const s16x8 one8 = {(short)0x3F80, (short)0x3F80, (short)0x3F80, (short)0x3F80,
                      (short)0x3F80, (short)0x3F80, (short)0x3F80, (short)0x3F80};

  // staging: 256 threads x 4 slots each for K and VT across the 128-token tile.
  // slot id = t + 256*j: sub = id>>9 (which 64-token subtile), row = (id&511)>>3,
  // b8 = id&7; LDS off = sub*4096 + row*64 + swizzle.
  int sub[4], rowj[4], b8j[4], soj[4];
#pragma unroll
  for (int j = 0; j < 4; ++j) {
    int id = t + 256 * j;
    sub[j] = id >> 9;
    int rid = id & 511;
    rowj[j] = rid >> 3;
    b8j[j] = rid & 7;
    soj[j] = sub[j] * 4096 + rowj[j] * 64 + ((b8j[j] ^ (rowj[j] & 7)) << 3);
  }
  const unsigned short* gK = K + (size_t)b * SS * 1536 + kvh * 64;
  const unsigned short* gV = VT + (size_t)(b * 4 + kvh) * 64 * SS;

  int4 rK[4], rV[4];
#pragma unroll
  for (int j = 0; j < 4; ++j) {            // stage tile 0 (tokens 0..127)
    rK[j] = *(const int4*)(gK + (size_t)(sub[j] * 64 + rowj[j]) * 1536 + b8j[j] * 8);
    rV[j] = *(const int4*)(gV + (size_t)rowj[j] * SS + sub[j] * 64 + b8j[j] * 8);
    *(int4*)&Ks[0][soj[j]] = rK[j];
    *(int4*)&VTs[0][soj[j]] = rV[j];
  }

  // mask base for this lane's q-row; stored pre-multiplied by LOG2E
  const float* mrowp = mask + (size_t)b * SS * SS + (size_t)(qt * 32 + q32) * SS + 4 * hi;
  float mc0[16], mc1[16];
#pragma unroll
  for (int j = 0; j < 4; ++j) {
    float4 v0 = *(const float4*)&mrowp[8 * j];
    float4 v1 = *(const float4*)&mrowp[32 + 8 * j];
    mc0[4 * j] = v0.x * LOG2E; mc0[4 * j + 1] = v0.y * LOG2E;
    mc0[4 * j + 2] = v0.z * LOG2E; mc0[4 * j + 3] = v0.w * LOG2E;
    mc1[4 * j] = v1.x * LOG2E; mc1[4 * j + 1] = v1.y * LOG2E;
    mc1[4 * j + 2] = v1.z * LOG2E; mc1[4 * j + 3] = v1.w * LOG2E;
  }

  f32x16 aco0 = {}, aco1 = {}, acl = {};
  float mrun = -1e30f;
  __syncthreads();

  for (int p = 0; p < 16; ++p) {
    const unsigned short* Kb = Ks[p & 1];
    const unsigned short* Vb = VTs[p & 1];
    if (p < 15) {    // prefetch next 128-token tile into regs (2 sub-steps of cover)
      int tb = (p + 1) * 128;
#pragma unroll
      for (int j = 0; j < 4; ++j) {
        rK[j] = *(const int4*)(gK + (size_t)(tb + sub[j] * 64 + rowj[j]) * 1536 + b8j[j] * 8);
        rV[j] = *(const int4*)(gV + (size_t)rowj[j] * SS + tb + sub[j] * 64 + b8j[j] * 8);
      }
    }
#pragma unroll
    for (int s = 0; s < 2; ++s) {
      int kt = p * 2 + s;
      const unsigned short* Kc = Kb + s * 4096;
      const unsigned short* Vc = Vb + s * 4096;
      // S^T = K . Q^T  (rows k, cols q=lane&31); two 32-k subtiles
      f32x16 s0 = {}, s1 = {};
      __builtin_amdgcn_s_setprio(1);
#pragma unroll
      for (int d = 0; d < 4; ++d) {
        s16x8 ka = *(const s16x8*)&Kc[q32 * 64 + (((d * 2 + hi) ^ (q32 & 7)) << 3)];
        s0 = mfma32(ka, qfr[d], s0);
        int r2 = 32 + q32;
        s16x8 kb2 = *(const s16x8*)&Kc[r2 * 64 + (((d * 2 + hi) ^ (r2 & 7)) << 3)];
        s1 = mfma32(kb2, qfr[d], s1);
      }
      __builtin_amdgcn_s_setprio(0);
      // log2-domain scores: one FMA per element
      float sv0[16], sv1[16];
#pragma unroll
      for (int r = 0; r < 16; ++r) {
        sv0[r] = s0[r] * SCL2 + mc0[r];
        sv1[r] = s1[r] * SCL2 + mc1[r];
      }
      // issue next kt's mask loads now (consumed next sub-step)
      {
        int nk = (kt < 31 ? kt + 1 : 31) * 64;
#pragma unroll
        for (int j = 0; j < 4; ++j) {
          float4 v0 = *(const float4*)&mrowp[nk + 8 * j];
          float4 v1 = *(const float4*)&mrowp[nk + 32 + 8 * j];
          mc0[4 * j] = v0.x * LOG2E; mc0[4 * j + 1] = v0.y * LOG2E;
          mc0[4 * j + 2] = v0.z * LOG2E; mc0[4 * j + 3] = v0.w * LOG2E;
          mc1[4 * j] = v1.x * LOG2E; mc1[4 * j + 1] = v1.y * LOG2E;
          mc1[4 * j + 2] = v1.z * LOG2E; mc1[4 * j + 3] = v1.w * LOG2E;
        }
      }
      // row max (lane-local q): reg tree + cross-half combine
      float mx = sv0[0];
#pragma unroll
      for (int r = 1; r < 16; ++r) mx = fmaxf(mx, sv0[r]);
#pragma unroll
      for (int r = 0; r < 16; ++r) mx = fmaxf(mx, sv1[r]);
      mx = fmaxf(mx, __shfl_xor(mx, 32));
      // defer-max rescale (rare)
      if (__any(mx > mrun + 8.0f)) {
        float mnew = fmaxf(mrun, mx);
        float alpha = fexp2(mrun - mnew);
        mrun = mnew;
#pragma unroll
        for (int r = 0; r < 16; ++r) {
          float al = __shfl(alpha, (r & 3) + 8 * (r >> 2) + 4 * hi);
          aco0[r] *= al; aco1[r] *= al; acl[r] *= al;
        }
      }
      // P = 2^(sv - mrun) -> bf16 pack -> cross-half exchange -> PV A-frags
      s16x8 pa[4];
#pragma unroll
      for (int ks = 0; ks < 2; ++ks) {
        float p2[16];
        if (ks == 0) {
#pragma unroll
          for (int r = 0; r < 16; ++r) p2[r] = fexp2(sv0[r] - mrun);
        } else {
#pragma unroll
          for (int r = 0; r < 16; ++r) p2[r] = fexp2(sv1[r] - mrun);
        }
        unsigned w8[8];
#pragma unroll
        for (int i = 0; i < 8; ++i) w8[i] = cvtpk(p2[2 * i], p2[2 * i + 1]);
        unsigned sd0 = hi ? w8[0] : w8[2];
        unsigned sd1 = hi ? w8[1] : w8[3];
        unsigned sd2 = hi ? w8[4] : w8[6];
        unsigned sd3 = hi ? w8[5] : w8[7];
        unsigned rc0 = (unsigned)__shfl_xor((int)sd0, 32);
        unsigned rc1 = (unsigned)__shfl_xor((int)sd1, 32);
        unsigned rc2 = (unsigned)__shfl_xor((int)sd2, 32);
        unsigned rc3 = (unsigned)__shfl_xor((int)sd3, 32);
        union { int4 i; s16x8 v; } fa, fb;
        fa.i.x = hi ? rc0 : w8[0]; fa.i.y = hi ? rc1 : w8[1];
        fa.i.z = hi ? w8[2] : rc0; fa.i.w = hi ? w8[3] : rc1;
        fb.i.x = hi ? rc2 : w8[4]; fb.i.y = hi ? rc3 : w8[5];
        fb.i.z = hi ? w8[6] : rc2; fb.i.w = hi ? w8[7] : rc3;
        pa[2 * ks] = fa.v;
        pa[2 * ks + 1] = fb.v;
      }
      // PV + denominator on matrix pipe
      __builtin_amdgcn_s_setprio(1);
#pragma unroll
      for (int ks = 0; ks < 4; ++ks) {
        s16x8 va = *(const s16x8*)&Vc[q32 * 64 + (((ks * 2 + hi) ^ (q32 & 7)) << 3)];
        aco0 = mfma32(pa[ks], va, aco0);
        int r2 = 32 + q32;
        s16x8 vb2 = *(const s16x8*)&Vc[r2 * 64 + (((ks * 2 + hi) ^ (r2 & 7)) << 3)];
        aco1 = mfma32(pa[ks], vb2, aco1);
        acl = mfma32(pa[ks], one8, acl);
      }
      __builtin_amdgcn_s_setprio(0);
    }
    if (p < 15) {    // publish prefetched tile p+1
      int nb = (p + 1) & 1;
#pragma unroll
      for (int j = 0; j < 4; ++j) {
        *(int4*)&Ks[nb][soj[j]] = rK[j];
        *(int4*)&VTs[nb][soj[j]] = rV[j];
      }
    }
    __syncthreads();   // single barrier per 128-token pair
  }
  // epilogue: rows follow crow(r,hi); cols = lane&31 (+dtile*32)
#pragma unroll
  for (int r = 0; r < 16; ++r) {
    float inv = 1.0f / acl[r];
    size_t orow = tokQ + (r & 3) + 8 * (r >> 2) + 4 * hi;
    Out[orow * 1024 + head * 64 + q32] = f2bf(aco0[r] * inv);
    Out[orow * 1024 + head * 64 + 32 + q32] = f2bf(aco1[r] * inv);
  }
}

extern "C" void kernel_launch(void* const* d_in, const int* in_sizes, int n_in,
                              void* d_out, int out_size, void* d_ws, size_t ws_size,
                              hipStream_t stream) {
  (void)in_sizes; (void)n_in; (void)out_size; (void)ws_size;
  const float* hidden = (const float*)d_in[0];
  const float* kvst   = (const float*)d_in[1];
  const float* maskp  = (const float*)d_in[2];
  const float* ln1    = (const float*)d_in[3];
  const float* ln2    = (const float*)d_in[4];
  const float* Wq     = (const float*)d_in[5];
  const float* Wk     = (const float*)d_in[6];
  const float* Wv     = (const float*)d_in[7];
  const float* Wo     = (const float*)d_in[8];
  const float* Wg     = (const float*)d_in[9];
  const float* Wu     = (const float*)d_in[10];
  const float* Wd     = (const float*)d_in[11];
  float* out = (float*)d_out;

  char* ws = (char*)d_ws;
  size_t off = 0;
  auto alloc = [&](size_t bytes) { char* p = ws + off; off += (bytes + 255) & ~(size_t)255; return p; };
  unsigned short* WTqkv = (unsigned short*)alloc((size_t)1536 * 1024 * 2);
  unsigned short* WTo   = (unsigned short*)alloc((size_t)1024 * 1024 * 2);
  unsigned short* WTg   = (unsigned short*)alloc((size_t)4096 * 1024 * 2);
  unsigned short* WTu   = (unsigned short*)alloc((size_t)4096 * 1024 * 2);
  unsigned short* WTd   = (unsigned short*)alloc((size_t)1024 * 4096 * 2);
  float* cosT           = (float*)alloc((size_t)2048 * 32 * 4);
  float* sinT           = (float*)alloc((size_t)2048 * 32 * 4);
  unsigned short* hn    = (unsigned short*)alloc((size_t)4096 * 1024 * 2);
  unsigned short* kvn   = (unsigned short*)alloc((size_t)4096 * 1024 * 2);
  unsigned short* QKVb  = (unsigned short*)alloc((size_t)4096 * 1536 * 2);
  unsigned short* VTg   = (unsigned short*)alloc((size_t)8 * 64 * SS * 2);
  float* hid2           = (float*)alloc((size_t)4096 * 1024 * 4);
  unsigned short* inter = (unsigned short*)alloc((size_t)4096 * 4096 * 2);
  unsigned short* attnb = hn;              // hn dead after Q-proj
  unsigned short* h2n   = kvn;             // kvn dead after KV-proj

  // weights -> bf16 transposed, same-shape pairs merged via blockIdx.z
  k_transpose<<<dim3(32, 32, 2), 256, 0, stream>>>(Wq, Wo, WTqkv, WTo, 1024, 1024);
  k_transpose<<<dim3(8, 32, 2), 256, 0, stream>>>(Wk, Wv, WTqkv + (size_t)1024 * 1024,
                                                  WTqkv + (size_t)1280 * 1024, 1024, 256);
  k_transpose<<<dim3(128, 32, 2), 256, 0, stream>>>(Wg, Wu, WTg, WTu, 1024, 4096);
  k_transpose<<<dim3(32, 128, 1), 256, 0, stream>>>(Wd, nullptr, WTd, nullptr, 4096, 1024);
  k_rope_tables<<<256, 256, 0, stream>>>(cosT, sinT);
  // both input norms in one launch (rows >= 4096 -> kv stream)
  k_rmsnorm<<<8192, 256, 0, stream>>>(hidden, kvst, ln1, hn, kvn);
  // projections into packed QKV [4096][1536]
  k_gemm<0, 64><<<dim3(16, 32), 256, 0, stream>>>(hn, WTqkv, 1024, 1536, QKVb, nullptr, nullptr);
  k_gemm<0, 64><<<dim3(8, 32), 256, 0, stream>>>(kvn, WTqkv + (size_t)1024 * 1024, 1024, 1536,
                                                 QKVb + 1024, nullptr, nullptr);
  // rope on K heads only (16..19); Q roped inside k_attn, V untouched
  k_rope<<<dim3(128, 4), 256, 0, stream>>>(QKVb, cosT, sinT, 1536, 16);
  // V^T for conflict-free attention staging
  k_vtrans<<<dim3(64, 2, 8), 256, 0, stream>>>(QKVb, VTg);
  // attention (4-wave blocks, 2/CU, fused Q-rope, KVBLK=128)
  k_attn<<<512, 256, 0, stream>>>(QKVb, QKVb + 1024, VTg, maskp, cosT, sinT, attnb);
  // O proj + residual
  k_gemm<1, 64><<<dim3(16, 32), 256, 0, stream>>>(attnb, WTo, 1024, 1024, nullptr, hid2, hidden);
  // MLP
  k_rmsnorm<<<4096, 256, 0, stream>>>(hid2, nullptr, ln2, h2n, nullptr);
  k_gateup<<<dim3(32, 32), 512, 0, stream>>>(h2n, WTg, WTu, inter);
  k_gemm<1, 64><<<dim3(16, 32), 256, 0, stream>>>(inter, WTd, 4096, 1024, nullptr, out, hid2);
}

// Round 21
// 291.248 us; speedup vs baseline: 1.3367x; 1.3367x over previous
//
#include <hip/hip_runtime.h>
#include <math.h>

#define SS 2048

typedef __attribute__((ext_vector_type(8))) short s16x8;
typedef __attribute__((ext_vector_type(4))) float f32x4;
typedef __attribute__((ext_vector_type(16))) float f32x16;

__device__ __forceinline__ unsigned short f2bf(float f) {
  union { float f; unsigned u; } a; a.f = f;
  unsigned r = a.u + 0x7fffu + ((a.u >> 16) & 1u);   // RNE
  return (unsigned short)(r >> 16);
}
__device__ __forceinline__ float bf2f(unsigned short b) {
  union { unsigned u; float f; } a; a.u = ((unsigned)b) << 16;
  return a.f;
}
// packed f32->bf16 (RNE): dword = {lo: bf16(a), hi: bf16(b)}
__device__ __forceinline__ unsigned cvtpk(float a, float b) {
  unsigned d; asm("v_cvt_pk_bf16_f32 %0, %1, %2" : "=v"(d) : "v"(a), "v"(b)); return d;
}
// raw v_exp_f32 = 2^x
__device__ __forceinline__ float fexp2(float x) {
  float r; asm("v_exp_f32 %0, %1" : "=v"(r) : "v"(x)); return r;
}
__device__ __forceinline__ void async16(void* lds, const void* g) {
  __builtin_amdgcn_global_load_lds(
      (const __attribute__((address_space(1))) unsigned int*)g,
      (__attribute__((address_space(3))) unsigned int*)lds, 16, 0, 0);
}
__device__ __forceinline__ f32x4 mfma_bf16(s16x8 a, s16x8 b, f32x4 c) {
  return __builtin_amdgcn_mfma_f32_16x16x32_bf16(a, b, c, 0, 0, 0);
}
__device__ __forceinline__ f32x16 mfma32(s16x8 a, s16x8 b, f32x16 c) {
  return __builtin_amdgcn_mfma_f32_32x32x16_bf16(a, b, c, 0, 0, 0);
}
// XCD-aware bijective blockIdx swizzle (T1); requires nwg % 8 == 0
__device__ __forceinline__ void xcd_swz(int& bx, int& by) {
  int nx = gridDim.x;
  int nwg = nx * gridDim.y;
  int bid = blockIdx.y * nx + blockIdx.x;
  int sid = (bid & 7) * (nwg >> 3) + (bid >> 3);
  bx = sid % nx; by = sid / nx;
}

// ---------- transpose + fp32->bf16: WT[n][k] = bf16(W[k][n]); z selects pair ----------
__global__ __launch_bounds__(256) void k_transpose(const float* __restrict__ W,
                                                   const float* __restrict__ W2,
                                                   unsigned short* __restrict__ WT,
                                                   unsigned short* __restrict__ WT2,
                                                   int K, int N) {
  const float* Wp = blockIdx.z ? W2 : W;
  unsigned short* WTp = blockIdx.z ? WT2 : WT;
  __shared__ float tile[32][33];
  int t = threadIdx.x;
  int tx = t & 31, ty = t >> 5;
  int n0 = blockIdx.x * 32, k0 = blockIdx.y * 32;
#pragma unroll
  for (int i = 0; i < 4; ++i)
    tile[ty + 8 * i][tx] = Wp[(size_t)(k0 + ty + 8 * i) * N + n0 + tx];
  __syncthreads();
#pragma unroll
  for (int i = 0; i < 4; ++i)
    WTp[(size_t)(n0 + ty + 8 * i) * K + k0 + tx] = f2bf(tile[tx][ty + 8 * i]);
}

// ---------- V^T precompute: VT[(b*4+kvh)][d=64][s=2048] from QKV cols 1280.. ----------
__global__ __launch_bounds__(256) void k_vtrans(const unsigned short* __restrict__ QKV,
                                                unsigned short* __restrict__ VT) {
  __shared__ unsigned short tile[32][33];
  int t = threadIdx.x, tx = t & 31, ty = t >> 5;
  int s0 = blockIdx.x * 32, d0 = blockIdx.y * 32;
  int bk = blockIdx.z; int b = bk >> 2, kvh = bk & 3;
#pragma unroll
  for (int i = 0; i < 4; ++i)
    tile[ty + 8 * i][tx] =
        QKV[((size_t)b * SS + s0 + ty + 8 * i) * 1536 + 1280 + kvh * 64 + d0 + tx];
  __syncthreads();
#pragma unroll
  for (int i = 0; i < 4; ++i)
    VT[((size_t)bk * 64 + d0 + ty + 8 * i) * SS + s0 + tx] = tile[tx][ty + 8 * i];
}

// ---------- RoPE tables (double precision, once per launch) ----------
__global__ void k_rope_tables(float* __restrict__ cosT, float* __restrict__ sinT) {
  int idx = blockIdx.x * 256 + threadIdx.x;  // 65536 = 2048*32
  int s = idx >> 5, i = idx & 31;
  double ang = (double)s * pow(10000.0, -(double)(2 * i) / 64.0);
  cosT[idx] = (float)cos(ang);
  sinT[idx] = (float)sin(ang);
}

// ---------- RMSNorm fp32 -> bf16; rows >= 4096 come from the second stream ----------
__global__ __launch_bounds__(256) void k_rmsnorm(const float* __restrict__ X,
                                                 const float* __restrict__ X2,
                                                 const float* __restrict__ Wt,
                                                 unsigned short* __restrict__ Y,
                                                 unsigned short* __restrict__ Y2) {
  int row = blockIdx.x, t = threadIdx.x;
  const float* Xp = X;
  unsigned short* Yp = Y;
  if (X2 && row >= 4096) { Xp = X2; Yp = Y2; row -= 4096; }
  float4 v = ((const float4*)Xp)[(size_t)row * 256 + t];
  float ssq = v.x * v.x + v.y * v.y + v.z * v.z + v.w * v.w;
#pragma unroll
  for (int m = 1; m < 64; m <<= 1) ssq += __shfl_xor(ssq, m);
  __shared__ float red[4];
  if ((t & 63) == 0) red[t >> 6] = ssq;
  __syncthreads();
  float sc = rsqrtf((red[0] + red[1] + red[2] + red[3]) * (1.0f / 1024.0f) + 1e-6f);
  float4 wv = ((const float4*)Wt)[t];
  ushort4 o;
  o.x = f2bf(v.x * sc * wv.x); o.y = f2bf(v.y * sc * wv.y);
  o.z = f2bf(v.z * sc * wv.z); o.w = f2bf(v.w * sc * wv.w);
  ((ushort4*)Yp)[(size_t)row * 256 + t] = o;
}

// ---------- RoPE in place on QKV buffer; head = blockIdx.y + hbase ----------
__global__ __launch_bounds__(256) void k_rope(unsigned short* __restrict__ X,
                                              const float* __restrict__ cosT,
                                              const float* __restrict__ sinT,
                                              int stride, int hbase) {
  int idx = blockIdx.x * 256 + threadIdx.x;  // tok*8+seg, tok 0..4095
  int seg = idx & 7, tok = idx >> 3;
  int head = blockIdx.y + hbase;
  int s = tok & (SS - 1);
  int d0 = seg * 4;
  unsigned short* p = X + (size_t)tok * stride + head * 64;
  ushort4 lo = *(ushort4*)&p[d0];
  ushort4 hi = *(ushort4*)&p[d0 + 32];
  float4 cs = *(const float4*)&cosT[s * 32 + d0];
  float4 sn = *(const float4*)&sinT[s * 32 + d0];
  ushort4 olo, ohi;
  olo.x = f2bf(bf2f(lo.x) * cs.x - bf2f(hi.x) * sn.x);
  olo.y = f2bf(bf2f(lo.y) * cs.y - bf2f(hi.y) * sn.y);
  olo.z = f2bf(bf2f(lo.z) * cs.z - bf2f(hi.z) * sn.z);
  olo.w = f2bf(bf2f(lo.w) * cs.w - bf2f(hi.w) * sn.w);
  ohi.x = f2bf(bf2f(hi.x) * cs.x + bf2f(lo.x) * sn.x);
  ohi.y = f2bf(bf2f(hi.y) * cs.y + bf2f(lo.y) * sn.y);
  ohi.z = f2bf(bf2f(hi.z) * cs.z + bf2f(lo.z) * sn.z);
  ohi.w = f2bf(bf2f(hi.w) * cs.w + bf2f(lo.w) * sn.w);
  *(ushort4*)&p[d0] = olo;
  *(ushort4*)&p[d0 + 32] = ohi;
}

// ---------- GEMM: C[M,N] = A[M,K](bf16) x BT[N,K](bf16), BK=64 + T2 swizzle ----------
template <int EPI, int BN>
__global__ __launch_bounds__(256) void k_gemm(const unsigned short* __restrict__ A,
                                              const unsigned short* __restrict__ BT,
                                              int K, int ldc,
                                              unsigned short* Cb,
                                              float* __restrict__ Cf,
                                              const float* __restrict__ Res) {
  constexpr int NW = BN / 32;
  __shared__ __align__(16) unsigned short at[128 * 64];
  __shared__ __align__(16) unsigned short bt[BN * 64];
  int bx, by; xcd_swz(bx, by);
  int t = threadIdx.x, w = t >> 6, l = t & 63;
  int g = l >> 4, c = l & 15;
  int wm = w >> 1, wn = w & 1;
  f32x4 acc[4][NW] = {};
  int srow = t >> 3;
  int scol = ((t & 7) ^ (srow & 7)) * 8;
  const unsigned short* gA = A + (size_t)(by * 128 + srow) * K + scol;
  const unsigned short* gB = BT + (size_t)(bx * BN + srow) * K + scol;
  unsigned short* dA = &at[w * 512];
  unsigned short* dB = &bt[w * 512];
  const int nk = K >> 6;
  for (int kt = 0; kt < nk; ++kt) {
#pragma unroll
    for (int j = 0; j < 4; ++j)
      async16(dA + j * 2048, gA + (size_t)(32 * j) * K);
#pragma unroll
    for (int j = 0; j < BN / 32; ++j)
      async16(dB + j * 2048, gB + (size_t)(32 * j) * K);
    gA += 64; gB += 64;
    __syncthreads();
    s16x8 af[4], bfr[NW];
#pragma unroll
    for (int kk = 0; kk < 2; ++kk) {
#pragma unroll
      for (int m = 0; m < 4; ++m)
        af[m] = *(const s16x8*)&at[(wm * 64 + m * 16 + c) * 64 + (((kk * 4 + g) ^ (c & 7)) << 3)];
#pragma unroll
      for (int n = 0; n < NW; ++n)
        bfr[n] = *(const s16x8*)&bt[(wn * (BN / 2) + n * 16 + c) * 64 + (((kk * 4 + g) ^ (c & 7)) << 3)];
#pragma unroll
      for (int m = 0; m < 4; ++m)
#pragma unroll
        for (int n = 0; n < NW; ++n)
          acc[m][n] = mfma_bf16(af[m], bfr[n], acc[m][n]);
    }
    __syncthreads();
  }
  size_t rb = (size_t)by * 128 + wm * 64;
  size_t cbase = (size_t)bx * BN + wn * (BN / 2);
#pragma unroll
  for (int m = 0; m < 4; ++m)
#pragma unroll
    for (int n = 0; n < NW; ++n)
#pragma unroll
      for (int r = 0; r < 4; ++r) {
        size_t row = rb + m * 16 + g * 4 + r;
        size_t col = cbase + n * 16 + c;
        float v = acc[m][n][r];
        if (EPI == 0) Cb[row * ldc + col] = f2bf(v);
        else Cf[row * ldc + col] = v + Res[row * ldc + col];
      }
}

// ---------- fused gate+up GEMM: inter = silu(A@Wg) * (A@Wu), BK=64 + T2 swizzle ----------
__global__ __launch_bounds__(512) void k_gateup(const unsigned short* __restrict__ A,
                                                const unsigned short* __restrict__ BTg,
                                                const unsigned short* __restrict__ BTu,
                                                unsigned short* __restrict__ Cb) {
  __shared__ __align__(16) unsigned short at[128 * 64];
  __shared__ __align__(16) unsigned short bg[128 * 64];
  __shared__ __align__(16) unsigned short bu[128 * 64];
  int bx, by; xcd_swz(bx, by);
  int t = threadIdx.x, w = t >> 6, l = t & 63;
  int g = l >> 4, c = l & 15;
  int wm = w >> 2, wn = w & 3;
  f32x4 ag[4][2] = {}, au[4][2] = {};
  int srow = t >> 3;
  int scol = ((t & 7) ^ (srow & 7)) * 8;
  const unsigned short* gA = A + (size_t)(by * 128 + srow) * 1024 + scol;
  const unsigned short* gG = BTg + (size_t)(bx * 128 + srow) * 1024 + scol;
  const unsigned short* gU = BTu + (size_t)(bx * 128 + srow) * 1024 + scol;
  unsigned short* dA = &at[w * 512];
  unsigned short* dG = &bg[w * 512];
  unsigned short* dU = &bu[w * 512];
  for (int kt = 0; kt < 16; ++kt) {
#pragma unroll
    for (int j = 0; j < 2; ++j) {
      async16(dA + j * 4096, gA + (size_t)(64 * j) * 1024);
      async16(dG + j * 4096, gG + (size_t)(64 * j) * 1024);
      async16(dU + j * 4096, gU + (size_t)(64 * j) * 1024);
    }
    gA += 64; gG += 64; gU += 64;
    __syncthreads();
    s16x8 af[4], bgf[2], buf_[2];
#pragma unroll
    for (int kk = 0; kk < 2; ++kk) {
#pragma unroll
      for (int m = 0; m < 4; ++m)
        af[m] = *(const s16x8*)&at[(wm * 64 + m * 16 + c) * 64 + (((kk * 4 + g) ^ (c & 7)) << 3)];
#pragma unroll
      for (int n = 0; n < 2; ++n) {
        int roff = (wn * 32 + n * 16 + c) * 64 + (((kk * 4 + g) ^ (c & 7)) << 3);
        bgf[n] = *(const s16x8*)&bg[roff];
        buf_[n] = *(const s16x8*)&bu[roff];
      }
#pragma unroll
      for (int m = 0; m < 4; ++m)
#pragma unroll
        for (int n = 0; n < 2; ++n) {
          ag[m][n] = mfma_bf16(af[m], bgf[n], ag[m][n]);
          au[m][n] = mfma_bf16(af[m], buf_[n], au[m][n]);
        }
    }
    __syncthreads();
  }
  size_t rb = (size_t)by * 128 + wm * 64;
  size_t cb = (size_t)bx * 128 + wn * 32;
#pragma unroll
  for (int m = 0; m < 4; ++m)
#pragma unroll
    for (int n = 0; n < 2; ++n)
#pragma unroll
      for (int r = 0; r < 4; ++r) {
        size_t row = rb + m * 16 + g * 4 + r;
        size_t col = cb + n * 16 + c;
        float gv = ag[m][n][r], uv = au[m][n][r];
        Cb[row * 4096 + col] = f2bf(gv / (1.0f + __expf(-gv)) * uv);
      }
}

// ---------- Flash attention, 32x32 swapped QK^T, Q-rope fused in prologue ----------
// Block = 256 thr = 4 waves = the 4 Q-heads of one GQA group; 32 q-rows per block.
// Measured constraint-box optimum: 32KB dbuf LDS (2 blocks/CU), 1 barrier/kt.
// R20's KVBLK=128 (64KB LDS) regressed 2.2x: LDS granularity rounded to 80KB ->
// 1 block/CU. Both LDS directions now falsified; this config is final.
__global__ __launch_bounds__(256) void k_attn(const unsigned short* __restrict__ Q,
                                              const unsigned short* __restrict__ K,
                                              const unsigned short* __restrict__ VT,
                                              const float* __restrict__ mask,
                                              const float* __restrict__ cosT,
                                              const float* __restrict__ sinT,
                                              unsigned short* __restrict__ Out) {
  __shared__ __align__(16) unsigned short Ks[2][64 * 64];
  __shared__ __align__(16) unsigned short VTs[2][64 * 64];
  const float LOG2E = 1.44269504f;
  const float SCL2 = 0.125f * 1.44269504f;
  int t = threadIdx.x, w = t >> 6, l = t & 63;
  int q32 = l & 31, hi = l >> 5;
  int blk = blockIdx.x;
  int qt = blk & 63, kvh = (blk >> 6) & 3, b = blk >> 8;
  int head = kvh * 4 + w;
  size_t tokQ = (size_t)b * SS + qt * 32;

  s16x8 qfr[4];   // Q[tokQ+q32][head*64 + d*16 + hi*8 + 0..7]
#pragma unroll
  for (int d = 0; d < 4; ++d)
    qfr[d] = *(const s16x8*)&Q[(tokQ + q32) * 1536 + head * 64 + d * 16 + hi * 8];
  // in-register RoPE on Q: dims d*16+hi*8+j; lo = d=0,1 (dims 0..31), hi-part = d+2
  {
    int sp = qt * 32 + q32;
    const float* ct = cosT + sp * 32;
    const float* st = sinT + sp * 32;
#pragma unroll
    for (int d = 0; d < 2; ++d) {
      unsigned wlo[4], whi[4];
#pragma unroll
      for (int j = 0; j < 8; j += 2) {
        int f0 = d * 16 + hi * 8 + j;
        float c0 = ct[f0], s0_ = st[f0];
        float c1 = ct[f0 + 1], s1_ = st[f0 + 1];
        float lo0 = bf2f((unsigned short)qfr[d][j]);
        float hi0 = bf2f((unsigned short)qfr[d + 2][j]);
        float lo1 = bf2f((unsigned short)qfr[d][j + 1]);
        float hi1 = bf2f((unsigned short)qfr[d + 2][j + 1]);
        wlo[j >> 1] = cvtpk(lo0 * c0 - hi0 * s0_, lo1 * c1 - hi1 * s1_);
        whi[j >> 1] = cvtpk(hi0 * c0 + lo0 * s0_, hi1 * c1 + lo1 * s1_);
      }
      union { unsigned u[4]; s16x8 v; } a, b2;
#pragma unroll
      for (int i = 0; i < 4; ++i) { a.u[i] = wlo[i]; b2.u[i] = whi[i]; }
      qfr[d] = a.v;
      qfr[d + 2] = b2.v;
    }
  }
  const s16x8 one8 = {(short)0x3F80, (short)0x3F80, (short)0x3F80, (short)0x3F80,
                      (short)0x3F80, (short)0x3F80, (short)0x3F80, (short)0x3F80};

  // staging: 256 threads x 2 slots each for K and VT (16B slots, XOR-swizzled)
  int id0 = t, id1 = t + 256;
  int row0 = id0 >> 3, b80 = id0 & 7;
  int row1 = id1 >> 3, b81 = id1 & 7;
  int so0 = row0 * 64 + ((b80 ^ (row0 & 7)) << 3);
  int so1 = row1 * 64 + ((b81 ^ (row1 & 7)) << 3);
  const unsigned short* gK = K + (size_t)b * SS * 1536 + kvh * 64;
  const unsigned short* gV = VT + (size_t)(b * 4 + kvh) * 64 * SS;

  int4 rK0 = *(const int4*)(gK + (size_t)row0 * 1536 + b80 * 8);
  int4 rK1 = *(const int4*)(gK + (size_t)row1 * 1536 + b81 * 8);
  int4 rV0 = *(const int4*)(gV + (size_t)row0 * SS + b80 * 8);
  int4 rV1 = *(const int4*)(gV + (size_t)row1 * SS + b81 * 8);
  *(int4*)&Ks[0][so0] = rK0; *(int4*)&Ks[0][so1] = rK1;
  *(int4*)&VTs[0][so0] = rV0; *(int4*)&VTs[0][so1] = rV1;

  // mask base for this lane's q-row; stored pre-multiplied by LOG2E
  const float* mrowp = mask + (size_t)b * SS * SS + (size_t)(qt * 32 + q32) * SS + 4 * hi;
  float mc0[16], mc1[16];
#pragma unroll
  for (int j = 0; j < 4; ++j) {
    float4 v0 = *(const float4*)&mrowp[8 * j];
    float4 v1 = *(const float4*)&mrowp[32 + 8 * j];
    mc0[4 * j] = v0.x * LOG2E; mc0[4 * j + 1] = v0.y * LOG2E;
    mc0[4 * j + 2] = v0.z * LOG2E; mc0[4 * j + 3] = v0.w * LOG2E;
    mc1[4 * j] = v1.x * LOG2E; mc1[4 * j + 1] = v1.y * LOG2E;
    mc1[4 * j + 2] = v1.z * LOG2E; mc1[4 * j + 3] = v1.w * LOG2E;
  }

  f32x16 aco0 = {}, aco1 = {}, acl = {};
  float mrun = -1e30f;
  __syncthreads();

  for (int kt = 0; kt < 32; ++kt) {
    const unsigned short* Kc = Ks[kt & 1];
    const unsigned short* Vc = VTs[kt & 1];
    if (kt < 31) {   // prefetch next tile into regs (published after MFMA)
      int kb = (kt + 1) * 64;
      rK0 = *(const int4*)(gK + (size_t)(kb + row0) * 1536 + b80 * 8);
      rK1 = *(const int4*)(gK + (size_t)(kb + row1) * 1536 + b81 * 8);
      rV0 = *(const int4*)(gV + (size_t)row0 * SS + kb + b80 * 8);
      rV1 = *(const int4*)(gV + (size_t)row1 * SS + kb + b81 * 8);
    }
    // S^T = K . Q^T  (rows k, cols q=lane&31); two 32-k subtiles
    f32x16 s0 = {}, s1 = {};
    __builtin_amdgcn_s_setprio(1);
#pragma unroll
    for (int d = 0; d < 4; ++d) {
      s16x8 ka = *(const s16x8*)&Kc[q32 * 64 + (((d * 2 + hi) ^ (q32 & 7)) << 3)];
      s0 = mfma32(ka, qfr[d], s0);
      int r2 = 32 + q32;
      s16x8 kb2 = *(const s16x8*)&Kc[r2 * 64 + (((d * 2 + hi) ^ (r2 & 7)) << 3)];
      s1 = mfma32(kb2, qfr[d], s1);
    }
    __builtin_amdgcn_s_setprio(0);
    // log2-domain scores: one FMA per element (mc pre-multiplied by LOG2E)
    float sv0[16], sv1[16];
#pragma unroll
    for (int r = 0; r < 16; ++r) {
      sv0[r] = s0[r] * SCL2 + mc0[r];
      sv1[r] = s1[r] * SCL2 + mc1[r];
    }
    // issue next tile's mask loads now (consumed next iter; latency hidden)
    {
      int nk = (kt < 31 ? kt + 1 : 31) * 64;
#pragma unroll
      for (int j = 0; j < 4; ++j) {
        float4 v0 = *(const float4*)&mrowp[nk + 8 * j];
        float4 v1 = *(const float4*)&mrowp[nk + 32 + 8 * j];
        mc0[4 * j] = v0.x * LOG2E; mc0[4 * j + 1] = v0.y * LOG2E;
        mc0[4 * j + 2] = v0.z * LOG2E; mc0[4 * j + 3] = v0.w * LOG2E;
        mc1[4 * j] = v1.x * LOG2E; mc1[4 * j + 1] = v1.y * LOG2E;
        mc1[4 * j + 2] = v1.z * LOG2E; mc1[4 * j + 3] = v1.w * LOG2E;
      }
    }
    // row max (lane-local q): reg tree + cross-half combine
    float mx = sv0[0];
#pragma unroll
    for (int r = 1; r < 16; ++r) mx = fmaxf(mx, sv0[r]);
#pragma unroll
    for (int r = 0; r < 16; ++r) mx = fmaxf(mx, sv1[r]);
    mx = fmaxf(mx, __shfl_xor(mx, 32));
    // defer-max rescale (rare); alpha redistributed to accumulator rows via shfl
    if (__any(mx > mrun + 8.0f)) {
      float mnew = fmaxf(mrun, mx);
      float alpha = fexp2(mrun - mnew);
      mrun = mnew;
#pragma unroll
      for (int r = 0; r < 16; ++r) {
        float al = __shfl(alpha, (r & 3) + 8 * (r >> 2) + 4 * hi);
        aco0[r] *= al; aco1[r] *= al; acl[r] *= al;
      }
    }
    // P = 2^(sv - mrun) -> bf16 pack -> cross-half exchange -> PV A-frags
    s16x8 pa[4];
#pragma unroll
    for (int ks = 0; ks < 2; ++ks) {
      float p[16];
      if (ks == 0) {
#pragma unroll
        for (int r = 0; r < 16; ++r) p[r] = fexp2(sv0[r] - mrun);
      } else {
#pragma unroll
        for (int r = 0; r < 16; ++r) p[r] = fexp2(sv1[r] - mrun);
      }
      unsigned w8[8];
#pragma unroll
      for (int i = 0; i < 8; ++i) w8[i] = cvtpk(p[2 * i], p[2 * i + 1]);
      unsigned sd0 = hi ? w8[0] : w8[2];
      unsigned sd1 = hi ? w8[1] : w8[3];
      unsigned sd2 = hi ? w8[4] : w8[6];
      unsigned sd3 = hi ? w8[5] : w8[7];
      unsigned rc0 = (unsigned)__shfl_xor((int)sd0, 32);
      unsigned rc1 = (unsigned)__shfl_xor((int)sd1, 32);
      unsigned rc2 = (unsigned)__shfl_xor((int)sd2, 32);
      unsigned rc3 = (unsigned)__shfl_xor((int)sd3, 32);
      union { int4 i; s16x8 v; } fa, fb;
      fa.i.x = hi ? rc0 : w8[0]; fa.i.y = hi ? rc1 : w8[1];
      fa.i.z = hi ? w8[2] : rc0; fa.i.w = hi ? w8[3] : rc1;
      fb.i.x = hi ? rc2 : w8[4]; fb.i.y = hi ? rc3 : w8[5];
      fb.i.z = hi ? w8[6] : rc2; fb.i.w = hi ? w8[7] : rc3;
      pa[2 * ks] = fa.v;
      pa[2 * ks + 1] = fb.v;
    }
    // PV + denominator on matrix pipe
    __builtin_amdgcn_s_setprio(1);
#pragma unroll
    for (int ks = 0; ks < 4; ++ks) {
      s16x8 va = *(const s16x8*)&Vc[q32 * 64 + (((ks * 2 + hi) ^ (q32 & 7)) << 3)];
      aco0 = mfma32(pa[ks], va, aco0);
      int r2 = 32 + q32;
      s16x8 vb2 = *(const s16x8*)&Vc[r2 * 64 + (((ks * 2 + hi) ^ (r2 & 7)) << 3)];
      aco1 = mfma32(pa[ks], vb2, aco1);
      acl = mfma32(pa[ks], one8, acl);
    }
    __builtin_amdgcn_s_setprio(0);
    if (kt < 31) {   // publish prefetched tile kt+1
      int nb = (kt + 1) & 1;
      *(int4*)&Ks[nb][so0] = rK0; *(int4*)&Ks[nb][so1] = rK1;
      *(int4*)&VTs[nb][so0] = rV0; *(int4*)&VTs[nb][so1] = rV1;
    }
    __syncthreads();   // single barrier per kt
  }
  // epilogue: rows follow crow(r,hi); cols = lane&31 (+dtile*32)
#pragma unroll
  for (int r = 0; r < 16; ++r) {
    float inv = 1.0f / acl[r];
    size_t orow = tokQ + (r & 3) + 8 * (r >> 2) + 4 * hi;
    Out[orow * 1024 + head * 64 + q32] = f2bf(aco0[r] * inv);
    Out[orow * 1024 + head * 64 + 32 + q32] = f2bf(aco1[r] * inv);
  }
}

extern "C" void kernel_launch(void* const* d_in, const int* in_sizes, int n_in,
                              void* d_out, int out_size, void* d_ws, size_t ws_size,
                              hipStream_t stream) {
  (void)in_sizes; (void)n_in; (void)out_size; (void)ws_size;
  const float* hidden = (const float*)d_in[0];
  const float* kvst   = (const float*)d_in[1];
  const float* maskp  = (const float*)d_in[2];
  const float* ln1    = (const float*)d_in[3];
  const float* ln2    = (const float*)d_in[4];
  const float* Wq     = (const float*)d_in[5];
  const float* Wk     = (const float*)d_in[6];
  const float* Wv     = (const float*)d_in[7];
  const float* Wo     = (const float*)d_in[8];
  const float* Wg     = (const float*)d_in[9];
  const float* Wu     = (const float*)d_in[10];
  const float* Wd     = (const float*)d_in[11];
  float* out = (float*)d_out;

  char* ws = (char*)d_ws;
  size_t off = 0;
  auto alloc = [&](size_t bytes) { char* p = ws + off; off += (bytes + 255) & ~(size_t)255; return p; };
  unsigned short* WTqkv = (unsigned short*)alloc((size_t)1536 * 1024 * 2);
  unsigned short* WTo   = (unsigned short*)alloc((size_t)1024 * 1024 * 2);
  unsigned short* WTg   = (unsigned short*)alloc((size_t)4096 * 1024 * 2);
  unsigned short* WTu   = (unsigned short*)alloc((size_t)4096 * 1024 * 2);
  unsigned short* WTd   = (unsigned short*)alloc((size_t)1024 * 4096 * 2);
  float* cosT           = (float*)alloc((size_t)2048 * 32 * 4);
  float* sinT           = (float*)alloc((size_t)2048 * 32 * 4);
  unsigned short* hn    = (unsigned short*)alloc((size_t)4096 * 1024 * 2);
  unsigned short* kvn   = (unsigned short*)alloc((size_t)4096 * 1024 * 2);
  unsigned short* QKVb  = (unsigned short*)alloc((size_t)4096 * 1536 * 2);
  unsigned short* VTg   = (unsigned short*)alloc((size_t)8 * 64 * SS * 2);
  float* hid2           = (float*)alloc((size_t)4096 * 1024 * 4);
  unsigned short* inter = (unsigned short*)alloc((size_t)4096 * 4096 * 2);
  unsigned short* attnb = hn;              // hn dead after Q-proj
  unsigned short* h2n   = kvn;             // kvn dead after KV-proj

  // weights -> bf16 transposed, same-shape pairs merged via blockIdx.z
  k_transpose<<<dim3(32, 32, 2), 256, 0, stream>>>(Wq, Wo, WTqkv, WTo, 1024, 1024);
  k_transpose<<<dim3(8, 32, 2), 256, 0, stream>>>(Wk, Wv, WTqkv + (size_t)1024 * 1024,
                                                  WTqkv + (size_t)1280 * 1024, 1024, 256);
  k_transpose<<<dim3(128, 32, 2), 256, 0, stream>>>(Wg, Wu, WTg, WTu, 1024, 4096);
  k_transpose<<<dim3(32, 128, 1), 256, 0, stream>>>(Wd, nullptr, WTd, nullptr, 4096, 1024);
  k_rope_tables<<<256, 256, 0, stream>>>(cosT, sinT);
  // both input norms in one launch (rows >= 4096 -> kv stream)
  k_rmsnorm<<<8192, 256, 0, stream>>>(hidden, kvst, ln1, hn, kvn);
  // projections into packed QKV [4096][1536]
  k_gemm<0, 64><<<dim3(16, 32), 256, 0, stream>>>(hn, WTqkv, 1024, 1536, QKVb, nullptr, nullptr);
  k_gemm<0, 64><<<dim3(8, 32), 256, 0, stream>>>(kvn, WTqkv + (size_t)1024 * 1024, 1024, 1536,
                                                 QKVb + 1024, nullptr, nullptr);
  // rope on K heads only (16..19); Q roped inside k_attn, V untouched
  k_rope<<<dim3(128, 4), 256, 0, stream>>>(QKVb, cosT, sinT, 1536, 16);
  // V^T for conflict-free attention staging
  k_vtrans<<<dim3(64, 2, 8), 256, 0, stream>>>(QKVb, VTg);
  // attention (4-wave blocks, 2/CU, fused Q-rope) — measured-best configuration
  k_attn<<<512, 256, 0, stream>>>(QKVb, QKVb + 1024, VTg, maskp, cosT, sinT, attnb);
  // O proj + residual
  k_gemm<1, 64><<<dim3(16, 32), 256, 0, stream>>>(attnb, WTo, 1024, 1024, nullptr, hid2, hidden);
  // MLP
  k_rmsnorm<<<4096, 256, 0, stream>>>(hid2, nullptr, ln2, h2n, nullptr);
  k_gateup<<<dim3(32, 32), 512, 0, stream>>>(h2n, WTg, WTu, inter);
  k_gemm<1, 64><<<dim3(16, 32), 256, 0, stream>>>(inter, WTd, 4096, 1024, nullptr, out, hid2);
}